// Round 4
// baseline (50633.502 us; speedup 1.0000x reference)
//
#include <hip/hip_runtime.h>
#include <cstdint>
#include <cstddef>

// Problem constants. Inputs/outputs are fp32 (established rounds 1-2).
constexpr int T_STEPS = 16384;
constexpr int D = 1024;
constexpr int G_WG = 64;    // recurrence workgroups
constexpr int C_COLS = 16;  // hidden columns owned per WG (G_WG * C_COLS == D)

typedef __attribute__((ext_vector_type(8))) short bf16x8;
typedef __attribute__((ext_vector_type(4))) float f32x4;

// Published hidden state: self-validating (tag<<32 | f32bits) words, double-
// buffered by step parity. Relaxed agent-scope atomics only — NO fences.
// R1 lesson: the publish/poll fine structure matters more than local compute:
//  * pend-latched polling (stop re-loading matched words) — removing it cost
//    +430MB FETCH and ~+200cyc/step of coherent-point contention.
//  * publish from ONE contiguous 16-lane group (128B region, single wave-level
//    store) — splitting across 4 waves cost +98MB WRITE (write-combining loss).
// Do not restructure these without an isolated A/B.
__device__ unsigned long long g_hpub[2 * D];

static __device__ __forceinline__ unsigned short f2bf(float f) {
  union { float f; unsigned int u; } v;
  v.f = f;
  unsigned int u = v.u;
  unsigned int r = (u + 0x7fffu + ((u >> 16) & 1u)) >> 16;  // RTN-even
  return (unsigned short)r;
}
static __device__ __forceinline__ unsigned int f_as_u(float f) {
  union { float f; unsigned int u; } v; v.f = f; return v.u;
}
static __device__ __forceinline__ float u_as_f(unsigned int u) {
  union { unsigned int u; float f; } v; v.u = u; return v.f;
}

__global__ void init_hpub() {
  const int i = blockIdx.x * 256 + threadIdx.x;
  if (i < 2 * D) g_hpub[i] = 0ull;  // tag 0 => never matches wanted tag >= 1
}

// ---------------------------------------------------------------------------
// GEMM: out[M][N] = A[M][K] @ B[K][N] + bias[N]; fp32 in/out, bf16 MFMA with
// fp32 accumulate. Tile 64x64, BK=32, 256 threads = 4 waves. (~100us/call;
// <1% of total — untouched.)
// ---------------------------------------------------------------------------
__global__ __launch_bounds__(256, 2) void gemm_bias(
    const float* __restrict__ A, const float* __restrict__ B,
    const float* __restrict__ bias, float* __restrict__ out, int M, int N,
    int K) {
  const int tid = threadIdx.x;
  const int wave = tid >> 6;
  const int lane = tid & 63;
  const int lrow = lane & 15;
  const int quad = lane >> 4;
  const int m0 = blockIdx.x * 64;
  const int n0 = blockIdx.y * 64;

  __shared__ __align__(16) unsigned short sA[64][40];  // stride 80B
  __shared__ __align__(16) unsigned short sB[32][68];  // stride 136B

  f32x4 acc[4];
#pragma unroll
  for (int s = 0; s < 4; ++s) acc[s] = (f32x4){0.f, 0.f, 0.f, 0.f};

  const int ar = tid >> 2;        // A stage row 0..63
  const int ac = (tid & 3) * 8;   // A stage col 0,8,16,24
  const int br = tid >> 3;        // B stage row 0..31
  const int bc = (tid & 7) * 8;   // B stage col 0..56

  for (int k0 = 0; k0 < K; k0 += 32) {
    union { unsigned short u[8]; uint4 v; } apk, bpk;
    {
      const float4 a0 = *(const float4*)(A + (size_t)(m0 + ar) * K + k0 + ac);
      const float4 a1 = *(const float4*)(A + (size_t)(m0 + ar) * K + k0 + ac + 4);
      apk.u[0] = f2bf(a0.x); apk.u[1] = f2bf(a0.y);
      apk.u[2] = f2bf(a0.z); apk.u[3] = f2bf(a0.w);
      apk.u[4] = f2bf(a1.x); apk.u[5] = f2bf(a1.y);
      apk.u[6] = f2bf(a1.z); apk.u[7] = f2bf(a1.w);
      const float4 b0 = *(const float4*)(B + (size_t)(k0 + br) * N + n0 + bc);
      const float4 b1 = *(const float4*)(B + (size_t)(k0 + br) * N + n0 + bc + 4);
      bpk.u[0] = f2bf(b0.x); bpk.u[1] = f2bf(b0.y);
      bpk.u[2] = f2bf(b0.z); bpk.u[3] = f2bf(b0.w);
      bpk.u[4] = f2bf(b1.x); bpk.u[5] = f2bf(b1.y);
      bpk.u[6] = f2bf(b1.z); bpk.u[7] = f2bf(b1.w);
    }

    __syncthreads();  // previous iteration's frag reads done
    *(uint4*)&sA[ar][ac] = apk.v;
    *(uint2*)&sB[br][bc] = make_uint2(bpk.v.x, bpk.v.y);
    *(uint2*)&sB[br][bc + 4] = make_uint2(bpk.v.z, bpk.v.w);
    __syncthreads();

    bf16x8 afrag = *(const bf16x8*)&sA[16 * wave + lrow][quad * 8];
#pragma unroll
    for (int s = 0; s < 4; ++s) {
      bf16x8 bfrag;
#pragma unroll
      for (int jj = 0; jj < 8; ++jj)
        bfrag[jj] = (short)sB[quad * 8 + jj][s * 16 + lrow];
      acc[s] = __builtin_amdgcn_mfma_f32_16x16x32_bf16(afrag, bfrag, acc[s], 0, 0, 0);
    }
  }

// epilogue: C/D layout col = lane&15, row = quad*4 + reg (m89-verified)
#pragma unroll
  for (int s = 0; s < 4; ++s) {
    const int col = n0 + s * 16 + lrow;
    const float bsv = bias[col];
#pragma unroll
    for (int r = 0; r < 4; ++r) {
      const int row = m0 + 16 * wave + quad * 4 + r;
      out[(size_t)row * N + col] = acc[s][r] + bsv;
    }
  }
}

// ---------------------------------------------------------------------------
// Recurrence: h_t = tanh(Apre[t] + h_{t-1} @ Wh), Hout[t] = h_t (fp32).
// 64 WGs x 256 threads, co-resident by capacity (1 block/CU).
//
// R3 FINDING: VGPR_Count=52 proves float W[64] was NEVER register-resident —
// the compiler rematerialized the (const __restrict__, loop-invariant) Wh
// loads INSIDE the t-loop: 64 L2 loads/thread/step on the serial critical
// path. That is why two rounds of matvec ILP / bank-conflict surgery moved
// nothing. Fix: opaque asm defs pin W[kk] into VGPRs (an asm result cannot
// be rematerialized as a load; at ~130 VGPR total vs 512 budget it won't
// spill). Everything else byte-identical to the R2 kernel.
// Expected: VGPR_Count >= 120 (diagnostic), step time down if W-reload was
// the dominant term.
// ---------------------------------------------------------------------------
__global__ __launch_bounds__(256, 1) void rnn_recur(
    const float* __restrict__ Apre, const float* __restrict__ Wh,
    float* __restrict__ Hout) {
  const int g = blockIdx.x;
  const int tid = threadIdx.x;
  const int j = tid & 15;   // column within WG slice
  const int rc = tid >> 4;  // row-chunk 0..15 (64 rows each)
  const int col = g * C_COLS + j;
  const int wave = tid >> 6;
  const int lane = tid & 63;

  // Wh slice into registers
  float W[64];
#pragma unroll
  for (int kk = 0; kk < 64; ++kk)
    W[kk] = Wh[(size_t)(rc * 64 + kk) * D + col];
  // Pin each W value to a VGPR: opaque def the compiler cannot
  // rematerialize as a global load inside the t-loop (R3 fix).
#pragma unroll
  for (int kk = 0; kk < 64; ++kk) asm volatile("" : "+v"(W[kk]));

  // h_{t-1} image, padded stride 68 (bank-conflict-free chunk bases)
  __shared__ __align__(16) float hl[16 * 68];
  __shared__ int sdead;
  __shared__ float red[64];
  if (tid == 0) sdead = 0;
  for (int i = tid; i < 16 * 68; i += 256) hl[i] = 0.f;  // h_{-1} = 0
  __syncthreads();

  float acur = Apre[col];  // A row for t=0
  int dead = 0;

  for (int t = 0; t < T_STEPS; ++t) {
    // prefetch next A row (hidden behind this step's compute+sync)
    float anext = 0.f;
    if (t + 1 < T_STEPS) anext = Apre[(size_t)(t + 1) * D + col];

    // partial dot over this thread's 64-row chunk; 4 independent
    // accumulators break the 64-deep fmaf dependency chain
    float a0 = 0.f, a1 = 0.f, a2 = 0.f, a3 = 0.f;
    const float4* hv = (const float4*)&hl[rc * 68];
#pragma unroll
    for (int kk = 0; kk < 16; ++kk) {
      float4 h4 = hv[kk];
      a0 = fmaf(W[4 * kk + 0], h4.x, a0);
      a1 = fmaf(W[4 * kk + 1], h4.y, a1);
      a2 = fmaf(W[4 * kk + 2], h4.z, a2);
      a3 = fmaf(W[4 * kk + 3], h4.w, a3);
    }
    float accv = (a0 + a1) + (a2 + a3);

    // reduce rc within wave: lanes L, L^16, L^32, L^48 share j
    accv += __shfl_xor(accv, 16);
    accv += __shfl_xor(accv, 32);
    if (lane < 16) red[wave * 16 + lane] = accv;
    __syncthreads();

    if (tid < 16) {
      float pre = acur + red[j] + red[16 + j] + red[32 + j] + red[48 + j];
      pre = fminf(fmaxf(pre, -30.f), 30.f);  // scrub any non-finite
      float h = tanhf(pre);
      Hout[(size_t)t * D + col] = h;
      const unsigned long long pk =
          ((unsigned long long)(unsigned)(t + 1) << 32) |
          (unsigned long long)f_as_u(h);
      __hip_atomic_store(&g_hpub[(t & 1) * D + col], pk, __ATOMIC_RELAXED,
                         __HIP_MEMORY_SCOPE_AGENT);
    }

    acur = anext;
    if (t + 1 == T_STEPS) break;

    // pull full h_t: poll 4 tagged words per thread until tag == t+1
    // (pend-latched: matched words are not re-loaded — R1 showed dropping
    // this costs +430MB FETCH and real time)
    if (!dead) {
      const unsigned int want = (unsigned)(t + 1);
      const int base = (t & 1) * D + tid * 4;
      const int hb = 4 * tid + 4 * (tid >> 4);  // padded LDS index of 4*tid
      int pend = 0xF;
      int spins = 0;
      do {
#pragma unroll
        for (int q = 0; q < 4; ++q) {
          if (pend & (1 << q)) {
            unsigned long long w = __hip_atomic_load(
                &g_hpub[base + q], __ATOMIC_RELAXED, __HIP_MEMORY_SCOPE_AGENT);
            if ((unsigned)(w >> 32) == want) {
              hl[hb + q] = u_as_f((unsigned)w);
              pend &= ~(1 << q);
            }
          }
        }
        if (!pend) break;
        if ((++spins & 7) == 7) __builtin_amdgcn_s_sleep(1);
        if (spins > (1 << 20)) { sdead = 1; break; }  // bailout: no hang
      } while (true);
    }
    __syncthreads();
    dead |= sdead;
  }
}

// ---------------------------------------------------------------------------
extern "C" void kernel_launch(void* const* d_in, const int* in_sizes, int n_in,
                              void* d_out, int out_size, void* d_ws,
                              size_t ws_size, hipStream_t stream) {
  const float* X  = (const float*)d_in[0];  // [T][D]
  const float* Wx = (const float*)d_in[1];  // [D][D]
  const float* Wh = (const float*)d_in[2];  // [D][D]
  const float* Wy = (const float*)d_in[3];  // [D][D]
  const float* bh = (const float*)d_in[4];  // [D]
  const float* by = (const float*)d_in[5];  // [D]

  float* Hout = (float*)d_out;              // hidden [T][D] fp32
  float* Yout = Hout + (size_t)T_STEPS * D; // outputs [T][D] fp32
  float* Apre = Yout;  // pre-activation scratch; overwritten by Y in phase 3

  const dim3 ggrid(T_STEPS / 64, D / 64);

  init_hpub<<<dim3((2 * D + 255) / 256), dim3(256), 0, stream>>>();

  // Phase 1: Apre = X @ Wx + bh
  gemm_bias<<<ggrid, dim3(256), 0, stream>>>(X, Wx, bh, Apre, T_STEPS, D, D);

  // Phase 2: sequential recurrence (64 co-resident WGs; tagged-word sync)
  rnn_recur<<<dim3(G_WG), dim3(256), 0, stream>>>(Apre, Wh, Hout);

  // Phase 3: Y = H @ Wy + by (overwrites Apre region)
  gemm_bias<<<ggrid, dim3(256), 0, stream>>>(Hout, Wy, by, Yout, T_STEPS, D, D);
}

// Round 5
// 39763.815 us; speedup vs baseline: 1.2734x; 1.2734x over previous
//
#include <hip/hip_runtime.h>
#include <cstdint>
#include <cstddef>

// Problem constants. Inputs/outputs are fp32 (established rounds 1-2).
constexpr int T_STEPS = 16384;
constexpr int D = 1024;
constexpr int G_WG = 64;    // recurrence workgroups
constexpr int C_COLS = 16;  // hidden columns owned per WG (G_WG * C_COLS == D)

typedef __attribute__((ext_vector_type(8))) short bf16x8;
typedef __attribute__((ext_vector_type(4))) float f32x4;

// Published hidden state: self-validating (tag<<32 | f32bits) words, double-
// buffered by step parity. Relaxed agent-scope atomics only — NO fences.
// R1 lesson: the publish/poll fine structure matters more than local compute:
//  * pend-latched polling (stop re-loading matched words) — removing it cost
//    +430MB FETCH and ~+200cyc/step of coherent-point contention.
//  * publish from ONE contiguous 16-lane group (128B region, single wave-level
//    store) — splitting across 4 waves cost +98MB WRITE (write-combining loss).
// Do not restructure these without an isolated A/B.
__device__ unsigned long long g_hpub[2 * D];

static __device__ __forceinline__ unsigned short f2bf(float f) {
  union { float f; unsigned int u; } v;
  v.f = f;
  unsigned int u = v.u;
  unsigned int r = (u + 0x7fffu + ((u >> 16) & 1u)) >> 16;  // RTN-even
  return (unsigned short)r;
}
static __device__ __forceinline__ unsigned int f_as_u(float f) {
  union { float f; unsigned int u; } v; v.f = f; return v.u;
}
static __device__ __forceinline__ float u_as_f(unsigned int u) {
  union { unsigned int u; float f; } v; v.u = u; return v.f;
}

__global__ void init_hpub() {
  const int i = blockIdx.x * 256 + threadIdx.x;
  if (i < 2 * D) g_hpub[i] = 0ull;  // tag 0 => never matches wanted tag >= 1
}

// ---------------------------------------------------------------------------
// GEMM: out[M][N] = A[M][K] @ B[K][N] + bias[N]; fp32 in/out, bf16 MFMA with
// fp32 accumulate. Tile 64x64, BK=32, 256 threads = 4 waves. (~100us/call;
// <1% of total — untouched.)
// ---------------------------------------------------------------------------
__global__ __launch_bounds__(256, 2) void gemm_bias(
    const float* __restrict__ A, const float* __restrict__ B,
    const float* __restrict__ bias, float* __restrict__ out, int M, int N,
    int K) {
  const int tid = threadIdx.x;
  const int wave = tid >> 6;
  const int lane = tid & 63;
  const int lrow = lane & 15;
  const int quad = lane >> 4;
  const int m0 = blockIdx.x * 64;
  const int n0 = blockIdx.y * 64;

  __shared__ __align__(16) unsigned short sA[64][40];  // stride 80B
  __shared__ __align__(16) unsigned short sB[32][68];  // stride 136B

  f32x4 acc[4];
#pragma unroll
  for (int s = 0; s < 4; ++s) acc[s] = (f32x4){0.f, 0.f, 0.f, 0.f};

  const int ar = tid >> 2;        // A stage row 0..63
  const int ac = (tid & 3) * 8;   // A stage col 0,8,16,24
  const int br = tid >> 3;        // B stage row 0..31
  const int bc = (tid & 7) * 8;   // B stage col 0..56

  for (int k0 = 0; k0 < K; k0 += 32) {
    union { unsigned short u[8]; uint4 v; } apk, bpk;
    {
      const float4 a0 = *(const float4*)(A + (size_t)(m0 + ar) * K + k0 + ac);
      const float4 a1 = *(const float4*)(A + (size_t)(m0 + ar) * K + k0 + ac + 4);
      apk.u[0] = f2bf(a0.x); apk.u[1] = f2bf(a0.y);
      apk.u[2] = f2bf(a0.z); apk.u[3] = f2bf(a0.w);
      apk.u[4] = f2bf(a1.x); apk.u[5] = f2bf(a1.y);
      apk.u[6] = f2bf(a1.z); apk.u[7] = f2bf(a1.w);
      const float4 b0 = *(const float4*)(B + (size_t)(k0 + br) * N + n0 + bc);
      const float4 b1 = *(const float4*)(B + (size_t)(k0 + br) * N + n0 + bc + 4);
      bpk.u[0] = f2bf(b0.x); bpk.u[1] = f2bf(b0.y);
      bpk.u[2] = f2bf(b0.z); bpk.u[3] = f2bf(b0.w);
      bpk.u[4] = f2bf(b1.x); bpk.u[5] = f2bf(b1.y);
      bpk.u[6] = f2bf(b1.z); bpk.u[7] = f2bf(b1.w);
    }

    __syncthreads();  // previous iteration's frag reads done
    *(uint4*)&sA[ar][ac] = apk.v;
    *(uint2*)&sB[br][bc] = make_uint2(bpk.v.x, bpk.v.y);
    *(uint2*)&sB[br][bc + 4] = make_uint2(bpk.v.z, bpk.v.w);
    __syncthreads();

    bf16x8 afrag = *(const bf16x8*)&sA[16 * wave + lrow][quad * 8];
#pragma unroll
    for (int s = 0; s < 4; ++s) {
      bf16x8 bfrag;
#pragma unroll
      for (int jj = 0; jj < 8; ++jj)
        bfrag[jj] = (short)sB[quad * 8 + jj][s * 16 + lrow];
      acc[s] = __builtin_amdgcn_mfma_f32_16x16x32_bf16(afrag, bfrag, acc[s], 0, 0, 0);
    }
  }

// epilogue: C/D layout col = lane&15, row = quad*4 + reg (m89-verified)
#pragma unroll
  for (int s = 0; s < 4; ++s) {
    const int col = n0 + s * 16 + lrow;
    const float bsv = bias[col];
#pragma unroll
    for (int r = 0; r < 4; ++r) {
      const int row = m0 + 16 * wave + quad * 4 + r;
      out[(size_t)row * N + col] = acc[s][r] + bsv;
    }
  }
}

// ---------------------------------------------------------------------------
// Recurrence: h_t = tanh(Apre[t] + h_{t-1} @ Wh), Hout[t] = h_t (fp32).
// 64 WGs x 256 threads, co-resident by capacity (1 block/CU).
//
// R4 FINDING: asm "+v" pins on float W[64] changed NOTHING (VGPR still 52,
// time still 39.1ms) => the array alloca was never promoted: W has lived in
// SCRATCH in every round, and the matvec re-loads 256B/thread (64KB/CU) from
// scratch/L2 EVERY STEP on the serial critical path (~1000-1400cyc of the
// ~5730cyc step). This is why ILP/padding/pinning all measured neutral.
// R5 fix: 16 individually NAMED float4 variables (macro-expanded, all field
// access static) — named structs are trivially SROA'd to SSA; asm defs after
// load make the values un-rematerializable. Budget 512 VGPR @ (256,1),
// expected pressure ~130. Everything else byte-identical to R4.
// Decisive diagnostic: VGPR_Count must jump to >=110. If time then stays
// ~39ms, the step is communication-RTT-bound (attack publish/poll next).
// ---------------------------------------------------------------------------
__global__ __launch_bounds__(256, 1) void rnn_recur(
    const float* __restrict__ Apre, const float* __restrict__ Wh,
    float* __restrict__ Hout) {
  const int g = blockIdx.x;
  const int tid = threadIdx.x;
  const int j = tid & 15;   // column within WG slice
  const int rc = tid >> 4;  // row-chunk 0..15 (64 rows each)
  const int col = g * C_COLS + j;
  const int wave = tid >> 6;
  const int lane = tid & 63;

  // Wh slice: 64 values as 16 NAMED float4s (SSA, not an alloca array).
  const float* wp = Wh + (size_t)(rc * 64) * D + col;
#define LOADW(i)                                                      \
  float4 w##i = make_float4(wp[(size_t)(4 * i + 0) * D],              \
                            wp[(size_t)(4 * i + 1) * D],              \
                            wp[(size_t)(4 * i + 2) * D],              \
                            wp[(size_t)(4 * i + 3) * D]);             \
  asm volatile("" : "+v"(w##i.x), "+v"(w##i.y), "+v"(w##i.z), "+v"(w##i.w));
  LOADW(0)  LOADW(1)  LOADW(2)  LOADW(3)
  LOADW(4)  LOADW(5)  LOADW(6)  LOADW(7)
  LOADW(8)  LOADW(9)  LOADW(10) LOADW(11)
  LOADW(12) LOADW(13) LOADW(14) LOADW(15)
#undef LOADW

  // h_{t-1} image, padded stride 68 (bank-conflict-free chunk bases)
  __shared__ __align__(16) float hl[16 * 68];
  __shared__ int sdead;
  __shared__ float red[64];
  if (tid == 0) sdead = 0;
  for (int i = tid; i < 16 * 68; i += 256) hl[i] = 0.f;  // h_{-1} = 0
  __syncthreads();

  float acur = Apre[col];  // A row for t=0
  int dead = 0;

  for (int t = 0; t < T_STEPS; ++t) {
    // prefetch next A row (hidden behind this step's compute+sync)
    float anext = 0.f;
    if (t + 1 < T_STEPS) anext = Apre[(size_t)(t + 1) * D + col];

    // partial dot over this thread's 64-row chunk; W in VGPRs, h from LDS,
    // 4 independent accumulators
    float a0 = 0.f, a1 = 0.f, a2 = 0.f, a3 = 0.f;
    const float4* hv = (const float4*)&hl[rc * 68];
#define FMA4(i)                                   \
  {                                               \
    float4 h4 = hv[i];                            \
    a0 = fmaf(w##i.x, h4.x, a0);                  \
    a1 = fmaf(w##i.y, h4.y, a1);                  \
    a2 = fmaf(w##i.z, h4.z, a2);                  \
    a3 = fmaf(w##i.w, h4.w, a3);                  \
  }
    FMA4(0)  FMA4(1)  FMA4(2)  FMA4(3)
    FMA4(4)  FMA4(5)  FMA4(6)  FMA4(7)
    FMA4(8)  FMA4(9)  FMA4(10) FMA4(11)
    FMA4(12) FMA4(13) FMA4(14) FMA4(15)
#undef FMA4
    float accv = (a0 + a1) + (a2 + a3);

    // reduce rc within wave: lanes L, L^16, L^32, L^48 share j
    accv += __shfl_xor(accv, 16);
    accv += __shfl_xor(accv, 32);
    if (lane < 16) red[wave * 16 + lane] = accv;
    __syncthreads();

    if (tid < 16) {
      float pre = acur + red[j] + red[16 + j] + red[32 + j] + red[48 + j];
      pre = fminf(fmaxf(pre, -30.f), 30.f);  // scrub any non-finite
      float h = tanhf(pre);
      Hout[(size_t)t * D + col] = h;
      const unsigned long long pk =
          ((unsigned long long)(unsigned)(t + 1) << 32) |
          (unsigned long long)f_as_u(h);
      __hip_atomic_store(&g_hpub[(t & 1) * D + col], pk, __ATOMIC_RELAXED,
                         __HIP_MEMORY_SCOPE_AGENT);
    }

    acur = anext;
    if (t + 1 == T_STEPS) break;

    // pull full h_t: poll 4 tagged words per thread until tag == t+1
    // (pend-latched: matched words are not re-loaded — R1 showed dropping
    // this costs +430MB FETCH and real time)
    if (!dead) {
      const unsigned int want = (unsigned)(t + 1);
      const int base = (t & 1) * D + tid * 4;
      const int hb = 4 * tid + 4 * (tid >> 4);  // padded LDS index of 4*tid
      int pend = 0xF;
      int spins = 0;
      do {
#pragma unroll
        for (int q = 0; q < 4; ++q) {
          if (pend & (1 << q)) {
            unsigned long long w = __hip_atomic_load(
                &g_hpub[base + q], __ATOMIC_RELAXED, __HIP_MEMORY_SCOPE_AGENT);
            if ((unsigned)(w >> 32) == want) {
              hl[hb + q] = u_as_f((unsigned)w);
              pend &= ~(1 << q);
            }
          }
        }
        if (!pend) break;
        if ((++spins & 7) == 7) __builtin_amdgcn_s_sleep(1);
        if (spins > (1 << 20)) { sdead = 1; break; }  // bailout: no hang
      } while (true);
    }
    __syncthreads();
    dead |= sdead;
  }
}

// ---------------------------------------------------------------------------
extern "C" void kernel_launch(void* const* d_in, const int* in_sizes, int n_in,
                              void* d_out, int out_size, void* d_ws,
                              size_t ws_size, hipStream_t stream) {
  const float* X  = (const float*)d_in[0];  // [T][D]
  const float* Wx = (const float*)d_in[1];  // [D][D]
  const float* Wh = (const float*)d_in[2];  // [D][D]
  const float* Wy = (const float*)d_in[3];  // [D][D]
  const float* bh = (const float*)d_in[4];  // [D]
  const float* by = (const float*)d_in[5];  // [D]

  float* Hout = (float*)d_out;              // hidden [T][D] fp32
  float* Yout = Hout + (size_t)T_STEPS * D; // outputs [T][D] fp32
  float* Apre = Yout;  // pre-activation scratch; overwritten by Y in phase 3

  const dim3 ggrid(T_STEPS / 64, D / 64);

  init_hpub<<<dim3((2 * D + 255) / 256), dim3(256), 0, stream>>>();

  // Phase 1: Apre = X @ Wx + bh
  gemm_bias<<<ggrid, dim3(256), 0, stream>>>(X, Wx, bh, Apre, T_STEPS, D, D);

  // Phase 2: sequential recurrence (64 co-resident WGs; tagged-word sync)
  rnn_recur<<<dim3(G_WG), dim3(256), 0, stream>>>(Apre, Wh, Hout);

  // Phase 3: Y = H @ Wy + by (overwrites Apre region)
  gemm_bias<<<ggrid, dim3(256), 0, stream>>>(Hout, Wy, by, Yout, T_STEPS, D, D);
}